// Round 5
// baseline (387.432 us; speedup 1.0000x reference)
//
#include <hip/hip_runtime.h>
#include <hip/hip_bf16.h>
#include <math.h>

#define NEG_SLOPE 0.2f
#define EPS_NRM 1e-12f
#define K_IN 256
#define C_OUT 64

typedef __attribute__((ext_vector_type(8))) short bf16x8;
typedef __attribute__((ext_vector_type(4))) float f32x4;

__device__ __forceinline__ unsigned short bf16_rne(float v) {
    unsigned u = __float_as_uint(v);
    return (unsigned short)((u + 0x7fffu + ((u >> 16) & 1u)) >> 16);
}

// ---------------------------------------------------------------------------
// Setup: split W (f32 [K][C]) into TRANSPOSED bf16 planes Wt_hi/Wt_lo
// ([col][k], contiguous k) so MFMA A-fragments are 16B contiguous loads.
// ---------------------------------------------------------------------------
__global__ __launch_bounds__(256) void wsplit(
    const float* __restrict__ W, unsigned short* __restrict__ Wt_hi,
    unsigned short* __restrict__ Wt_lo)
{
    int tid = blockIdx.x * blockDim.x + threadIdx.x;
    if (tid >= K_IN * C_OUT) return;
    int k = tid >> 6, c = tid & 63;          // C_OUT = 64
    float v = W[tid];
    unsigned short hb = bf16_rne(v);
    float vh = __uint_as_float((unsigned)hb << 16);
    unsigned short lb = bf16_rne(v - vh);
    Wt_hi[c * K_IN + k] = hb;
    Wt_lo[c * K_IN + k] = lb;
}

// ---------------------------------------------------------------------------
// Kernel A: h = x @ W via split-bf16 MFMA, ZERO LDS / ZERO BARRIERS.
// r4 post-mortem: LDS-staged MFMA version had MfmaUtil 3.3% + VALU 8% +
// occ 25% -- every pipe idle; the {load->convert->LDS->barrier->read->MFMA
// ->barrier} chain at 2-3 blocks/CU was pure dependency stall. Structural
// fact: with swapped operands (a=W-frag, b=x-frag) the x-fragments are
// WAVE-PRIVATE (b-frag: row=l&15, k=grp*8+j). So stage nothing: each wave
// loads its 16 x-rows global->reg in fragment order (16 rows x 128B fully
// consumed per k-tile), converts in-reg, MFMAs. W-frags (64KB, all-GPU
// shared) come straight from L2. 16 rows/wave -> 6250 waves, 1563 blocks,
// all co-resident at LDS=0; compiler pipelines freely with no syncs.
// Frag maps (r4-verified, passed): a: row=l&15,k=grp*8+j; b: col(row m)=
// l&15,k=grp*8+j; D: m=l&15, c=grp*4+j (per coltile n: cols n*16+grp*4+j).
// FUSED: dst-degree histogram (grid-stride) after the epilogue.
// ---------------------------------------------------------------------------
__global__ __launch_bounds__(256) void gemm_att(
    const float* __restrict__ x,
    const unsigned short* __restrict__ Wt_hi,
    const unsigned short* __restrict__ Wt_lo,
    const float* __restrict__ att_s, const float* __restrict__ att_d,
    __hip_bfloat16* __restrict__ h, float* __restrict__ a_src_arr,
    float* __restrict__ a_dst_arr, int N,
    const int* __restrict__ dstA, int* __restrict__ cnt, int E)
{
    int t   = threadIdx.x;
    int gw  = (blockIdx.x * blockDim.x + t) >> 6;   // global wave id
    int l   = t & 63;
    int lm  = l & 15;        // x-row within rowtile / W-col within coltile
    int grp = l >> 4;        // k-subchunk 8*grp..8*grp+7 ; D cols grp*4+j
    int row0 = gw * 16;

    int srow = row0 + lm; if (srow >= N) srow = N - 1;
    const float* xq = x + (size_t)srow * K_IN + grp * 8;

    // W-fragment base for this lane (per coltile n add n*16 rows)
    const unsigned short* wbh = Wt_hi + (size_t)lm * K_IN + grp * 8;
    const unsigned short* wbl = Wt_lo + (size_t)lm * K_IN + grp * 8;

    f32x4 acc[4];
#pragma unroll
    for (int n = 0; n < 4; ++n) acc[n] = (f32x4){0.f, 0.f, 0.f, 0.f};

    float4 xa = *(const float4*)(xq);
    float4 xb = *(const float4*)(xq + 4);

    for (int kt = 0; kt < K_IN / 32; ++kt) {
        float4 xa2, xb2;
        if (kt < K_IN / 32 - 1) {   // prefetch next k-chunk
            xa2 = *(const float4*)(xq + (kt + 1) * 32);
            xb2 = *(const float4*)(xq + (kt + 1) * 32 + 4);
        }
        // convert 8 f32 -> hi/lo bf16x8 (Markidis split, ~f32 accuracy)
        short sh[8], sl[8];
        const float* fa = (const float*)&xa;
        const float* fb = (const float*)&xb;
#pragma unroll
        for (int i = 0; i < 4; ++i) {
            float v0 = fa[i], v1 = fb[i];
            unsigned short h0 = bf16_rne(v0), h1 = bf16_rne(v1);
            sh[i] = (short)h0; sh[i + 4] = (short)h1;
            sl[i]     = (short)bf16_rne(v0 - __uint_as_float((unsigned)h0 << 16));
            sl[i + 4] = (short)bf16_rne(v1 - __uint_as_float((unsigned)h1 << 16));
        }
        bf16x8 xh = *(bf16x8*)&sh[0];
        bf16x8 xl = *(bf16x8*)&sl[0];

        int ko = kt * 32;
#pragma unroll
        for (int n = 0; n < 4; ++n) {
            bf16x8 wh = *(const bf16x8*)(wbh + (size_t)n * 16 * K_IN + ko);
            bf16x8 wl = *(const bf16x8*)(wbl + (size_t)n * 16 * K_IN + ko);
            acc[n] = __builtin_amdgcn_mfma_f32_16x16x32_bf16(wh, xh, acc[n], 0, 0, 0);
            acc[n] = __builtin_amdgcn_mfma_f32_16x16x32_bf16(wl, xh, acc[n], 0, 0, 0);
            acc[n] = __builtin_amdgcn_mfma_f32_16x16x32_bf16(wh, xl, acc[n], 0, 0, 0);
        }
        xa = xa2; xb = xb2;
    }

    // ---- epilogue: scores + bf16 h store ----
    // lane's cols: n*16 + grp*4 + j ; lane's row: row0 + lm
    int row = row0 + lm;
    float ps = 0.f, pd = 0.f;
#pragma unroll
    for (int n = 0; n < 4; ++n) {
        float4 as4 = *(const float4*)(att_s + n * 16 + grp * 4);
        float4 ad4 = *(const float4*)(att_d + n * 16 + grp * 4);
        f32x4 a = acc[n];
        ps += a.x * as4.x + a.y * as4.y + a.z * as4.z + a.w * as4.w;
        pd += a.x * ad4.x + a.y * ad4.y + a.z * ad4.z + a.w * ad4.w;
    }
    ps += __shfl_xor(ps, 16, 64); ps += __shfl_xor(ps, 32, 64);
    pd += __shfl_xor(pd, 16, 64); pd += __shfl_xor(pd, 32, 64);
    if (row < N) {
        if (grp == 0) { a_src_arr[row] = ps; a_dst_arr[row] = pd; }
#pragma unroll
        for (int n = 0; n < 4; ++n) {
            f32x4 a = acc[n];
            __hip_bfloat16 b0 = __float2bfloat16(a.x);
            __hip_bfloat16 b1 = __float2bfloat16(a.y);
            __hip_bfloat16 b2 = __float2bfloat16(a.z);
            __hip_bfloat16 b3 = __float2bfloat16(a.w);
            unsigned long long pk =
                (unsigned long long)*(unsigned short*)&b0 |
                ((unsigned long long)*(unsigned short*)&b1 << 16) |
                ((unsigned long long)*(unsigned short*)&b2 << 32) |
                ((unsigned long long)*(unsigned short*)&b3 << 48);
            *(unsigned long long*)(h + (size_t)row * C_OUT + n * 16 + grp * 4) = pk;
        }
    }

    // ---- fused dst-degree histogram (independent of the GEMM above) ----
    int stride = gridDim.x * blockDim.x;
    for (int i = blockIdx.x * blockDim.x + t; i < E; i += stride)
        atomicAdd(&cnt[dstA[i]], 1);
}

// ---------------------------------------------------------------------------
// Scan over counts (self loops folded into gat_pull, no +1).
// ---------------------------------------------------------------------------
__global__ __launch_bounds__(256) void scan_p1(
    const int* __restrict__ cnt, int* __restrict__ partials, int n)
{
    int b = blockIdx.x, t = threadIdx.x;
    int base = b * 1024;
    int s = 0;
#pragma unroll
    for (int j = 0; j < 4; ++j) {
        int i = base + t * 4 + j;
        if (i < n) s += cnt[i];
    }
    for (int d = 1; d < 64; d <<= 1) s += __shfl_xor(s, d, 64);
    __shared__ int wsum[4];
    int lane = t & 63, wid = t >> 6;
    if (lane == 0) wsum[wid] = s;
    __syncthreads();
    if (t == 0) partials[b] = wsum[0] + wsum[1] + wsum[2] + wsum[3];
}

__global__ __launch_bounds__(256) void scan_p2(int* partials, int nb)
{
    __shared__ int buf[256];
    int t = threadIdx.x;
    int v = (t < nb) ? partials[t] : 0;
    buf[t] = v;
    __syncthreads();
    for (int d = 1; d < 256; d <<= 1) {
        int w = (t >= d) ? buf[t - d] : 0;
        __syncthreads();
        buf[t] += w;
        __syncthreads();
    }
    if (t < nb) partials[t] = buf[t] - v;  // exclusive
}

__global__ __launch_bounds__(256) void scan_p3(
    const int* __restrict__ cnt, const int* __restrict__ partials,
    int* __restrict__ offsets, int n)
{
    int b = blockIdx.x, t = threadIdx.x;
    int base = b * 1024;
    int v[4];
    int s = 0;
#pragma unroll
    for (int j = 0; j < 4; ++j) {
        int i = base + t * 4 + j;
        v[j] = (i < n) ? cnt[i] : 0;
        s += v[j];
    }
    int lane = t & 63, wid = t >> 6;
    int incl = s;
    for (int d = 1; d < 64; d <<= 1) {
        int w = __shfl_up(incl, d, 64);
        if (lane >= d) incl += w;
    }
    __shared__ int wsum[4];
    __shared__ int wbase[4];
    if (lane == 63) wsum[wid] = incl;
    __syncthreads();
    if (t == 0) {
        int r = 0;
        for (int i = 0; i < 4; ++i) { wbase[i] = r; r += wsum[i]; }
    }
    __syncthreads();
    int run = partials[b] + wbase[wid] + (incl - s);
#pragma unroll
    for (int j = 0; j < 4; ++j) {
        int i = base + t * 4 + j;
        if (i < n) {
            offsets[i] = run;
            run += v[j];
            if (i == n - 1) offsets[n] = run;
        }
    }
}

// Packed {src, w} entry via NONTEMPORAL store: skips write-allocate (no line
// fetch) and keeps random 8B stores out of L2 — attacks the E*64B partial-
// line writeback storm (round-6/7 counter evidence). atomicExch variant
// regressed (r7: 129us); plain store baseline is 85us.
__global__ __launch_bounds__(256) void scatter_edges(
    const int* __restrict__ srcA, const int* __restrict__ dstA,
    const int* __restrict__ offsets, int* __restrict__ cursor,
    const float* __restrict__ a_src, const float* __restrict__ a_dst,
    unsigned long long* __restrict__ csr, int E)
{
    int i = blockIdx.x * blockDim.x + threadIdx.x;
    if (i >= E) return;
    int s = srcA[i], d = dstA[i];
    float e = a_src[s] + a_dst[d];
    e = fmaxf(e, NEG_SLOPE * e);
    float w = __expf(e);
    int pos = offsets[d] + atomicAdd(&cursor[d], 1);
    unsigned long long packed =
        (unsigned long long)(unsigned)s |
        ((unsigned long long)__float_as_uint(w) << 32);
    __builtin_nontemporal_store(packed, &csr[pos]);
}

// ---------------------------------------------------------------------------
// Kernel C: QUARTER-WAVE per node — 16 lanes/node, lane covers 4 bf16 cols
// (one 8B load per edge). Self-loop term computed analytically.
// ---------------------------------------------------------------------------
__global__ __launch_bounds__(256) void gat_pull(
    const int* __restrict__ offsets, const int2* __restrict__ csr,
    const unsigned short* __restrict__ h, const float* __restrict__ a_src,
    const float* __restrict__ a_dst, const float* __restrict__ bias,
    float* __restrict__ out, int N)
{
    int gw   = (blockIdx.x * blockDim.x + threadIdx.x) >> 6;  // wave id
    int lane = threadIdx.x & 63;
    int grp  = lane >> 4;        // 0..3 : node within wave
    int gl   = lane & 15;        // lane within group; cols 4*gl..4*gl+3
    int node = gw * 4 + grp;
    bool valid = node < N;
    int nv = valid ? node : 0;

    int beg = offsets[nv];
    int n   = valid ? (offsets[nv + 1] - beg) : 0;   // may be 0
    const int2* ce = csr + (n ? beg : 0);

    // self-loop term (always present in reference softmax)
    float asv = a_src[nv], adv = a_dst[nv];
    float es = asv + adv; es = fmaxf(es, NEG_SLOPE * es);
    float ws = __expf(es);
    unsigned long long hu = *(const unsigned long long*)
        (h + (size_t)nv * C_OUT + 4 * gl);
    unsigned hl = (unsigned)hu, hh = (unsigned)(hu >> 32);
    float acc0 = ws * __uint_as_float(hl << 16);
    float acc1 = ws * __uint_as_float(hl & 0xffff0000u);
    float acc2 = ws * __uint_as_float(hh << 16);
    float acc3 = ws * __uint_as_float(hh & 0xffff0000u);
    float den = ws;

    // 2-deep pipelined edge loop
    int2 c0 = ce[0];
    int2 c1 = ce[(n > 1) ? 1 : 0];
    unsigned long long u0 = *(const unsigned long long*)
        (h + (size_t)c0.x * C_OUT + 4 * gl);
    unsigned long long u1 = *(const unsigned long long*)
        (h + (size_t)c1.x * C_OUT + 4 * gl);

    for (int p = 0; p < n; p += 2) {
        int2 m0 = ce[(p + 2 < n) ? p + 2 : 0];
        int2 m1 = ce[(p + 3 < n) ? p + 3 : 0];
        unsigned long long v0 = *(const unsigned long long*)
            (h + (size_t)m0.x * C_OUT + 4 * gl);
        unsigned long long v1 = *(const unsigned long long*)
            (h + (size_t)m1.x * C_OUT + 4 * gl);

        float w0 = __int_as_float(c0.y);
        float w1 = (p + 1 < n) ? __int_as_float(c1.y) : 0.f;
        unsigned l0 = (unsigned)u0, h0 = (unsigned)(u0 >> 32);
        unsigned l1 = (unsigned)u1, h1 = (unsigned)(u1 >> 32);
        den  += w0 + w1;
        acc0 += w0 * __uint_as_float(l0 << 16)
              + w1 * __uint_as_float(l1 << 16);
        acc1 += w0 * __uint_as_float(l0 & 0xffff0000u)
              + w1 * __uint_as_float(l1 & 0xffff0000u);
        acc2 += w0 * __uint_as_float(h0 << 16)
              + w1 * __uint_as_float(h1 << 16);
        acc3 += w0 * __uint_as_float(h0 & 0xffff0000u)
              + w1 * __uint_as_float(h1 & 0xffff0000u);

        c0 = m0; c1 = m1; u0 = v0; u1 = v1;
    }

    float4 bl = *(const float4*)(bias + 4 * gl);
    float rd = 1.f / den;
    float o0 = acc0 * rd + bl.x;
    float o1 = acc1 * rd + bl.y;
    float o2 = acc2 * rd + bl.z;
    float o3 = acc3 * rd + bl.w;

    // L2 norm within the 16-lane group (xor d=1..8 stays in-group)
    float sq = o0 * o0 + o1 * o1 + o2 * o2 + o3 * o3;
#pragma unroll
    for (int d = 1; d < 16; d <<= 1) sq += __shfl_xor(sq, d, 64);
    float rn = 1.f / fmaxf(sqrtf(sq), EPS_NRM);

    if (valid)
        *(float4*)(out + (size_t)node * C_OUT + 4 * gl) =
            make_float4(o0 * rn, o1 * rn, o2 * rn, o3 * rn);
}

// ---------------------------------------------------------------------------
extern "C" void kernel_launch(void* const* d_in, const int* in_sizes, int n_in,
                              void* d_out, int out_size, void* d_ws, size_t ws_size,
                              hipStream_t stream)
{
    const float* x     = (const float*)d_in[0];
    const int*   ei    = (const int*)d_in[1];   // [2][E], row0=src, row1=dst
    const float* W     = (const float*)d_in[2];
    const float* att_s = (const float*)d_in[3];
    const float* att_d = (const float*)d_in[4];
    const float* bias  = (const float*)d_in[5];
    float*       out   = (float*)d_out;

    const int OUT = in_sizes[3];          // 64
    const int IN  = in_sizes[2] / OUT;    // 256
    const int N   = in_sizes[0] / IN;     // 100000
    const int E   = in_sizes[1] / 2;      // 1600000

    // workspace carve-out (256B aligned) — ~27.7 MB total
    char* w = (char*)d_ws;
    auto alloc = [&](size_t bytes) -> void* {
        void* p = (void*)w;
        w += (bytes + 255) & ~(size_t)255;
        return p;
    };
    __hip_bfloat16* h = (__hip_bfloat16*)alloc((size_t)N * C_OUT * 2);
    float* a_src  = (float*)alloc((size_t)N * 4);
    float* a_dst  = (float*)alloc((size_t)N * 4);
    int*   cnt    = (int*)alloc((size_t)N * 2 * 4);  // [0..N) hist, [N..2N) cursor
    int*   offs   = (int*)alloc((size_t)(N + 1) * 4);
    int*   parts  = (int*)alloc(1024 * 4);
    unsigned short* Wt_hi = (unsigned short*)alloc((size_t)K_IN * C_OUT * 2);
    unsigned short* Wt_lo = (unsigned short*)alloc((size_t)K_IN * C_OUT * 2);
    unsigned long long* csr = (unsigned long long*)alloc((size_t)E * 8);
    int*   cursor = cnt + N;

    hipMemsetAsync(cnt, 0, (size_t)N * 2 * 4, stream);

    wsplit<<<(K_IN * C_OUT + 255) / 256, 256, 0, stream>>>(W, Wt_hi, Wt_lo);

    // 16 rows per wave, 4 waves per block -> 64 rows/block
    gemm_att<<<(N + 63) / 64, 256, 0, stream>>>(
        x, Wt_hi, Wt_lo, att_s, att_d, h, a_src, a_dst, N, ei + E, cnt, E);

    int NB = (N + 1023) / 1024;
    scan_p1<<<NB, 256, 0, stream>>>(cnt, parts, N);
    scan_p2<<<1, 256, 0, stream>>>(parts, NB);
    scan_p3<<<NB, 256, 0, stream>>>(cnt, parts, offs, N);

    scatter_edges<<<(E + 255) / 256, 256, 0, stream>>>(
        ei, ei + E, offs, cursor, a_src, a_dst, csr, E);

    // quarter-wave: 16 nodes per 256-thread block
    gat_pull<<<(N + 15) / 16, 256, 0, stream>>>(offs, (const int2*)csr,
        (const unsigned short*)h, a_src, a_dst, bias, out, N);
}

// Round 6
// 374.048 us; speedup vs baseline: 1.0358x; 1.0358x over previous
//
#include <hip/hip_runtime.h>
#include <hip/hip_bf16.h>
#include <math.h>

#define NEG_SLOPE 0.2f
#define EPS_NRM 1e-12f
#define K_IN 256
#define C_OUT 64

typedef __attribute__((ext_vector_type(8))) short bf16x8;
typedef __attribute__((ext_vector_type(4))) float f32x4;

__device__ __forceinline__ unsigned short bf16_rne(float v) {
    unsigned u = __float_as_uint(v);
    return (unsigned short)((u + 0x7fffu + ((u >> 16) & 1u)) >> 16);
}

// ---------------------------------------------------------------------------
// Setup: split W (f32 [K][C]) into TRANSPOSED bf16 planes Wt_hi/Wt_lo
// ([col][k], contiguous k) so MFMA A-fragments are 16B contiguous loads.
// ---------------------------------------------------------------------------
__global__ __launch_bounds__(256) void wsplit(
    const float* __restrict__ W, unsigned short* __restrict__ Wt_hi,
    unsigned short* __restrict__ Wt_lo)
{
    int tid = blockIdx.x * blockDim.x + threadIdx.x;
    if (tid >= K_IN * C_OUT) return;
    int k = tid >> 6, c = tid & 63;          // C_OUT = 64
    float v = W[tid];
    unsigned short hb = bf16_rne(v);
    float vh = __uint_as_float((unsigned)hb << 16);
    unsigned short lb = bf16_rne(v - vh);
    Wt_hi[c * K_IN + k] = hb;
    Wt_lo[c * K_IN + k] = lb;
}

// ---------------------------------------------------------------------------
// Kernel A: h = x @ W via split-bf16 MFMA, zero LDS / zero barriers,
// PLUS the dst-degree histogram with RANK CAPTURE, issued FIRST.
// r5 post-mortem: 4 structurally different GEMMs all landed at 96-128us
// with ALL pipes idle -> the invariant cost is the 1.6M device-scope
// histogram atomics serialized AFTER the GEMM (corroborated: scatter's
// 1.6M returning atomics = 85us, ~50us per 1M random far-atomics).
// Fix: (a) make the histogram atomic RETURNING and keep the value as the
// edge's rank within its dst (stored at kernel end) -> scatter_edges
// needs NO atomics at all; (b) issue the histogram at kernel START of
// this barrier-free kernel so the atomic queue overlaps the MFMA work
// (returns consumed only by the final rank stores).
// GEMM: wave-private x fragments (b-frag: row=l&15, k=grp*8+j), W-frags
// straight from L2, 16 rows/wave, no staging (r4/r5-verified frag maps).
// ---------------------------------------------------------------------------
__global__ __launch_bounds__(256) void gemm_att(
    const float* __restrict__ x,
    const unsigned short* __restrict__ Wt_hi,
    const unsigned short* __restrict__ Wt_lo,
    const float* __restrict__ att_s, const float* __restrict__ att_d,
    __hip_bfloat16* __restrict__ h, float* __restrict__ a_src_arr,
    float* __restrict__ a_dst_arr, int N,
    const int* __restrict__ dstA, int* __restrict__ cnt,
    int* __restrict__ rank, int E)
{
    int t      = threadIdx.x;
    int gtid   = blockIdx.x * blockDim.x + t;
    int stride = gridDim.x * blockDim.x;

    // ---- fused histogram + rank capture, ISSUED FIRST (overlaps GEMM) ----
    int r0 = 0, r1 = 0, r2 = 0, r3 = 0;
    int i0 = gtid, i1 = gtid + stride, i2 = gtid + 2 * stride,
        i3 = gtid + 3 * stride;
    if (i0 < E) r0 = atomicAdd(&cnt[dstA[i0]], 1);
    if (i1 < E) r1 = atomicAdd(&cnt[dstA[i1]], 1);
    if (i2 < E) r2 = atomicAdd(&cnt[dstA[i2]], 1);
    if (i3 < E) r3 = atomicAdd(&cnt[dstA[i3]], 1);
    // generality tail (never taken at N=100K/E=1.6M): store immediately
    for (int i = gtid + 4 * stride; i < E; i += stride)
        rank[i] = atomicAdd(&cnt[dstA[i]], 1);

    // ---- GEMM ----
    int gw  = gtid >> 6;     // global wave id
    int l   = t & 63;
    int lm  = l & 15;        // x-row within rowtile / W-col within coltile
    int grp = l >> 4;        // k-subchunk 8*grp..8*grp+7 ; D cols grp*4+j
    int row0 = gw * 16;

    int srow = row0 + lm; if (srow >= N) srow = N - 1;
    const float* xq = x + (size_t)srow * K_IN + grp * 8;

    const unsigned short* wbh = Wt_hi + (size_t)lm * K_IN + grp * 8;
    const unsigned short* wbl = Wt_lo + (size_t)lm * K_IN + grp * 8;

    f32x4 acc[4];
#pragma unroll
    for (int n = 0; n < 4; ++n) acc[n] = (f32x4){0.f, 0.f, 0.f, 0.f};

    float4 xa = *(const float4*)(xq);
    float4 xb = *(const float4*)(xq + 4);

    for (int kt = 0; kt < K_IN / 32; ++kt) {
        float4 xa2, xb2;
        if (kt < K_IN / 32 - 1) {   // prefetch next k-chunk
            xa2 = *(const float4*)(xq + (kt + 1) * 32);
            xb2 = *(const float4*)(xq + (kt + 1) * 32 + 4);
        }
        // convert 8 f32 -> hi/lo bf16x8 (Markidis split, ~f32 accuracy)
        short sh[8], sl[8];
        const float* fa = (const float*)&xa;
        const float* fb = (const float*)&xb;
#pragma unroll
        for (int i = 0; i < 4; ++i) {
            float v0 = fa[i], v1 = fb[i];
            unsigned short h0 = bf16_rne(v0), h1 = bf16_rne(v1);
            sh[i] = (short)h0; sh[i + 4] = (short)h1;
            sl[i]     = (short)bf16_rne(v0 - __uint_as_float((unsigned)h0 << 16));
            sl[i + 4] = (short)bf16_rne(v1 - __uint_as_float((unsigned)h1 << 16));
        }
        bf16x8 xh = *(bf16x8*)&sh[0];
        bf16x8 xl = *(bf16x8*)&sl[0];

        int ko = kt * 32;
#pragma unroll
        for (int n = 0; n < 4; ++n) {
            bf16x8 wh = *(const bf16x8*)(wbh + (size_t)n * 16 * K_IN + ko);
            bf16x8 wl = *(const bf16x8*)(wbl + (size_t)n * 16 * K_IN + ko);
            acc[n] = __builtin_amdgcn_mfma_f32_16x16x32_bf16(wh, xh, acc[n], 0, 0, 0);
            acc[n] = __builtin_amdgcn_mfma_f32_16x16x32_bf16(wl, xh, acc[n], 0, 0, 0);
            acc[n] = __builtin_amdgcn_mfma_f32_16x16x32_bf16(wh, xl, acc[n], 0, 0, 0);
        }
        xa = xa2; xb = xb2;
    }

    // ---- epilogue: scores + bf16 h store ----
    int row = row0 + lm;
    float ps = 0.f, pd = 0.f;
#pragma unroll
    for (int n = 0; n < 4; ++n) {
        float4 as4 = *(const float4*)(att_s + n * 16 + grp * 4);
        float4 ad4 = *(const float4*)(att_d + n * 16 + grp * 4);
        f32x4 a = acc[n];
        ps += a.x * as4.x + a.y * as4.y + a.z * as4.z + a.w * as4.w;
        pd += a.x * ad4.x + a.y * ad4.y + a.z * ad4.z + a.w * ad4.w;
    }
    ps += __shfl_xor(ps, 16, 64); ps += __shfl_xor(ps, 32, 64);
    pd += __shfl_xor(pd, 16, 64); pd += __shfl_xor(pd, 32, 64);
    if (row < N) {
        if (grp == 0) { a_src_arr[row] = ps; a_dst_arr[row] = pd; }
#pragma unroll
        for (int n = 0; n < 4; ++n) {
            f32x4 a = acc[n];
            __hip_bfloat16 b0 = __float2bfloat16(a.x);
            __hip_bfloat16 b1 = __float2bfloat16(a.y);
            __hip_bfloat16 b2 = __float2bfloat16(a.z);
            __hip_bfloat16 b3 = __float2bfloat16(a.w);
            unsigned long long pk =
                (unsigned long long)*(unsigned short*)&b0 |
                ((unsigned long long)*(unsigned short*)&b1 << 16) |
                ((unsigned long long)*(unsigned short*)&b2 << 32) |
                ((unsigned long long)*(unsigned short*)&b3 << 48);
            *(unsigned long long*)(h + (size_t)row * C_OUT + n * 16 + grp * 4) = pk;
        }
    }

    // ---- store captured ranks (atomic returns long since landed) ----
    if (i0 < E) rank[i0] = r0;
    if (i1 < E) rank[i1] = r1;
    if (i2 < E) rank[i2] = r2;
    if (i3 < E) rank[i3] = r3;
}

// ---------------------------------------------------------------------------
// Scan over counts (self loops folded into gat_pull, no +1).
// ---------------------------------------------------------------------------
__global__ __launch_bounds__(256) void scan_p1(
    const int* __restrict__ cnt, int* __restrict__ partials, int n)
{
    int b = blockIdx.x, t = threadIdx.x;
    int base = b * 1024;
    int s = 0;
#pragma unroll
    for (int j = 0; j < 4; ++j) {
        int i = base + t * 4 + j;
        if (i < n) s += cnt[i];
    }
    for (int d = 1; d < 64; d <<= 1) s += __shfl_xor(s, d, 64);
    __shared__ int wsum[4];
    int lane = t & 63, wid = t >> 6;
    if (lane == 0) wsum[wid] = s;
    __syncthreads();
    if (t == 0) partials[b] = wsum[0] + wsum[1] + wsum[2] + wsum[3];
}

__global__ __launch_bounds__(256) void scan_p2(int* partials, int nb)
{
    __shared__ int buf[256];
    int t = threadIdx.x;
    int v = (t < nb) ? partials[t] : 0;
    buf[t] = v;
    __syncthreads();
    for (int d = 1; d < 256; d <<= 1) {
        int w = (t >= d) ? buf[t - d] : 0;
        __syncthreads();
        buf[t] += w;
        __syncthreads();
    }
    if (t < nb) partials[t] = buf[t] - v;  // exclusive
}

__global__ __launch_bounds__(256) void scan_p3(
    const int* __restrict__ cnt, const int* __restrict__ partials,
    int* __restrict__ offsets, int n)
{
    int b = blockIdx.x, t = threadIdx.x;
    int base = b * 1024;
    int v[4];
    int s = 0;
#pragma unroll
    for (int j = 0; j < 4; ++j) {
        int i = base + t * 4 + j;
        v[j] = (i < n) ? cnt[i] : 0;
        s += v[j];
    }
    int lane = t & 63, wid = t >> 6;
    int incl = s;
    for (int d = 1; d < 64; d <<= 1) {
        int w = __shfl_up(incl, d, 64);
        if (lane >= d) incl += w;
    }
    __shared__ int wsum[4];
    __shared__ int wbase[4];
    if (lane == 63) wsum[wid] = incl;
    __syncthreads();
    if (t == 0) {
        int r = 0;
        for (int i = 0; i < 4; ++i) { wbase[i] = r; r += wsum[i]; }
    }
    __syncthreads();
    int run = partials[b] + wbase[wid] + (incl - s);
#pragma unroll
    for (int j = 0; j < 4; ++j) {
        int i = base + t * 4 + j;
        if (i < n) {
            offsets[i] = run;
            run += v[j];
            if (i == n - 1) offsets[n] = run;
        }
    }
}

// ---------------------------------------------------------------------------
// scatter_edges, NOW ATOMIC-FREE: pos = offs[d] + rank[i] (rank captured
// from the histogram's returning atomic in gemm_att). Previously the
// returning cursor atomic made this kernel ~85us; now it's pure
// load/compute/nontemporal-store.
// ---------------------------------------------------------------------------
__global__ __launch_bounds__(256) void scatter_edges(
    const int* __restrict__ srcA, const int* __restrict__ dstA,
    const int* __restrict__ offsets, const int* __restrict__ rank,
    const float* __restrict__ a_src, const float* __restrict__ a_dst,
    unsigned long long* __restrict__ csr, int E)
{
    int i = blockIdx.x * blockDim.x + threadIdx.x;
    if (i >= E) return;
    int s = srcA[i], d = dstA[i];
    float e = a_src[s] + a_dst[d];
    e = fmaxf(e, NEG_SLOPE * e);
    float w = __expf(e);
    int pos = offsets[d] + rank[i];
    unsigned long long packed =
        (unsigned long long)(unsigned)s |
        ((unsigned long long)__float_as_uint(w) << 32);
    __builtin_nontemporal_store(packed, &csr[pos]);
}

// ---------------------------------------------------------------------------
// Kernel C: QUARTER-WAVE per node — 16 lanes/node, lane covers 4 bf16 cols
// (one 8B load per edge). Self-loop term computed analytically.
// ---------------------------------------------------------------------------
__global__ __launch_bounds__(256) void gat_pull(
    const int* __restrict__ offsets, const int2* __restrict__ csr,
    const unsigned short* __restrict__ h, const float* __restrict__ a_src,
    const float* __restrict__ a_dst, const float* __restrict__ bias,
    float* __restrict__ out, int N)
{
    int gw   = (blockIdx.x * blockDim.x + threadIdx.x) >> 6;  // wave id
    int lane = threadIdx.x & 63;
    int grp  = lane >> 4;        // 0..3 : node within wave
    int gl   = lane & 15;        // lane within group; cols 4*gl..4*gl+3
    int node = gw * 4 + grp;
    bool valid = node < N;
    int nv = valid ? node : 0;

    int beg = offsets[nv];
    int n   = valid ? (offsets[nv + 1] - beg) : 0;   // may be 0
    const int2* ce = csr + (n ? beg : 0);

    // self-loop term (always present in reference softmax)
    float asv = a_src[nv], adv = a_dst[nv];
    float es = asv + adv; es = fmaxf(es, NEG_SLOPE * es);
    float ws = __expf(es);
    unsigned long long hu = *(const unsigned long long*)
        (h + (size_t)nv * C_OUT + 4 * gl);
    unsigned hl = (unsigned)hu, hh = (unsigned)(hu >> 32);
    float acc0 = ws * __uint_as_float(hl << 16);
    float acc1 = ws * __uint_as_float(hl & 0xffff0000u);
    float acc2 = ws * __uint_as_float(hh << 16);
    float acc3 = ws * __uint_as_float(hh & 0xffff0000u);
    float den = ws;

    // 2-deep pipelined edge loop
    int2 c0 = ce[0];
    int2 c1 = ce[(n > 1) ? 1 : 0];
    unsigned long long u0 = *(const unsigned long long*)
        (h + (size_t)c0.x * C_OUT + 4 * gl);
    unsigned long long u1 = *(const unsigned long long*)
        (h + (size_t)c1.x * C_OUT + 4 * gl);

    for (int p = 0; p < n; p += 2) {
        int2 m0 = ce[(p + 2 < n) ? p + 2 : 0];
        int2 m1 = ce[(p + 3 < n) ? p + 3 : 0];
        unsigned long long v0 = *(const unsigned long long*)
            (h + (size_t)m0.x * C_OUT + 4 * gl);
        unsigned long long v1 = *(const unsigned long long*)
            (h + (size_t)m1.x * C_OUT + 4 * gl);

        float w0 = __int_as_float(c0.y);
        float w1 = (p + 1 < n) ? __int_as_float(c1.y) : 0.f;
        unsigned l0 = (unsigned)u0, h0 = (unsigned)(u0 >> 32);
        unsigned l1 = (unsigned)u1, h1 = (unsigned)(u1 >> 32);
        den  += w0 + w1;
        acc0 += w0 * __uint_as_float(l0 << 16)
              + w1 * __uint_as_float(l1 << 16);
        acc1 += w0 * __uint_as_float(l0 & 0xffff0000u)
              + w1 * __uint_as_float(l1 & 0xffff0000u);
        acc2 += w0 * __uint_as_float(h0 << 16)
              + w1 * __uint_as_float(h1 << 16);
        acc3 += w0 * __uint_as_float(h0 & 0xffff0000u)
              + w1 * __uint_as_float(h1 & 0xffff0000u);

        c0 = m0; c1 = m1; u0 = v0; u1 = v1;
    }

    float4 bl = *(const float4*)(bias + 4 * gl);
    float rd = 1.f / den;
    float o0 = acc0 * rd + bl.x;
    float o1 = acc1 * rd + bl.y;
    float o2 = acc2 * rd + bl.z;
    float o3 = acc3 * rd + bl.w;

    // L2 norm within the 16-lane group (xor d=1..8 stays in-group)
    float sq = o0 * o0 + o1 * o1 + o2 * o2 + o3 * o3;
#pragma unroll
    for (int d = 1; d < 16; d <<= 1) sq += __shfl_xor(sq, d, 64);
    float rn = 1.f / fmaxf(sqrtf(sq), EPS_NRM);

    if (valid)
        *(float4*)(out + (size_t)node * C_OUT + 4 * gl) =
            make_float4(o0 * rn, o1 * rn, o2 * rn, o3 * rn);
}

// ---------------------------------------------------------------------------
extern "C" void kernel_launch(void* const* d_in, const int* in_sizes, int n_in,
                              void* d_out, int out_size, void* d_ws, size_t ws_size,
                              hipStream_t stream)
{
    const float* x     = (const float*)d_in[0];
    const int*   ei    = (const int*)d_in[1];   // [2][E], row0=src, row1=dst
    const float* W     = (const float*)d_in[2];
    const float* att_s = (const float*)d_in[3];
    const float* att_d = (const float*)d_in[4];
    const float* bias  = (const float*)d_in[5];
    float*       out   = (float*)d_out;

    const int OUT = in_sizes[3];          // 64
    const int IN  = in_sizes[2] / OUT;    // 256
    const int N   = in_sizes[0] / IN;     // 100000
    const int E   = in_sizes[1] / 2;      // 1600000

    // workspace carve-out (256B aligned) — ~34 MB total
    char* w = (char*)d_ws;
    auto alloc = [&](size_t bytes) -> void* {
        void* p = (void*)w;
        w += (bytes + 255) & ~(size_t)255;
        return p;
    };
    __hip_bfloat16* h = (__hip_bfloat16*)alloc((size_t)N * C_OUT * 2);
    float* a_src  = (float*)alloc((size_t)N * 4);
    float* a_dst  = (float*)alloc((size_t)N * 4);
    int*   cnt    = (int*)alloc((size_t)N * 4);
    int*   offs   = (int*)alloc((size_t)(N + 1) * 4);
    int*   parts  = (int*)alloc(1024 * 4);
    unsigned short* Wt_hi = (unsigned short*)alloc((size_t)K_IN * C_OUT * 2);
    unsigned short* Wt_lo = (unsigned short*)alloc((size_t)K_IN * C_OUT * 2);
    int*   rank   = (int*)alloc((size_t)E * 4);
    unsigned long long* csr = (unsigned long long*)alloc((size_t)E * 8);

    hipMemsetAsync(cnt, 0, (size_t)N * 4, stream);

    wsplit<<<(K_IN * C_OUT + 255) / 256, 256, 0, stream>>>(W, Wt_hi, Wt_lo);

    // 16 rows per wave, 4 waves per block -> 64 rows/block
    gemm_att<<<(N + 63) / 64, 256, 0, stream>>>(
        x, Wt_hi, Wt_lo, att_s, att_d, h, a_src, a_dst, N, ei + E, cnt,
        rank, E);

    int NB = (N + 1023) / 1024;
    scan_p1<<<NB, 256, 0, stream>>>(cnt, parts, N);
    scan_p2<<<1, 256, 0, stream>>>(parts, NB);
    scan_p3<<<NB, 256, 0, stream>>>(cnt, parts, offs, N);

    scatter_edges<<<(E + 255) / 256, 256, 0, stream>>>(
        ei, ei + E, offs, rank, a_src, a_dst, csr, E);

    // quarter-wave: 16 nodes per 256-thread block
    gat_pull<<<(N + 15) / 16, 256, 0, stream>>>(offs, (const int2*)csr,
        (const unsigned short*)h, a_src, a_dst, bias, out, N);
}

// Round 7
// 367.352 us; speedup vs baseline: 1.0547x; 1.0182x over previous
//
#include <hip/hip_runtime.h>
#include <hip/hip_bf16.h>
#include <math.h>

#define NEG_SLOPE 0.2f
#define EPS_NRM 1e-12f
#define K_IN 256
#define C_OUT 64

typedef __attribute__((ext_vector_type(8))) short bf16x8;
typedef __attribute__((ext_vector_type(4))) float f32x4;

__device__ __forceinline__ unsigned short bf16_rne(float v) {
    unsigned u = __float_as_uint(v);
    return (unsigned short)((u + 0x7fffu + ((u >> 16) & 1u)) >> 16);
}

// ---------------------------------------------------------------------------
// Setup: split W (f32 [K][C]) into TRANSPOSED bf16 planes Wt_hi/Wt_lo
// ([col][k], contiguous k) so MFMA A-fragments are 16B contiguous loads.
// ---------------------------------------------------------------------------
__global__ __launch_bounds__(256) void wsplit(
    const float* __restrict__ W, unsigned short* __restrict__ Wt_hi,
    unsigned short* __restrict__ Wt_lo)
{
    int tid = blockIdx.x * blockDim.x + threadIdx.x;
    if (tid >= K_IN * C_OUT) return;
    int k = tid >> 6, c = tid & 63;          // C_OUT = 64
    float v = W[tid];
    unsigned short hb = bf16_rne(v);
    float vh = __uint_as_float((unsigned)hb << 16);
    unsigned short lb = bf16_rne(v - vh);
    Wt_hi[c * K_IN + k] = hb;
    Wt_lo[c * K_IN + k] = lb;
}

// ---------------------------------------------------------------------------
// Kernel A: h = x @ W via split-bf16 MFMA (zero LDS / zero barriers) +
// dst-degree histogram with rank capture, WAVE-PARITY STAGGERED.
// r6 post-mortem: atomics-at-front stalled every wave's GEMM behind its own
// atomic returns (vmcnt retires IN ISSUE ORDER: waiting for a later load
// drains earlier atomics) -> 139us serial. r5's atomics-at-end = 128us:
// lockstep waves all hit the atomic phase together, ~80us drain with no
// compute left (1.6M device atomics ~ 20G/s device floor, invariant across
// r1-r6). Fix: STAGGER -- even waves issue atomics before the GEMM (stall
// on queue position while odd waves compute), odd waves after the epilogue
// (drain overlapped by even waves' GEMM). Queue saturated from t=0.
// GEMM: wave-private x fragments (b-frag: row=l&15, k=grp*8+j), W-frags
// straight from L2, 16 rows/wave, no staging (r4/r5-verified frag maps).
// ---------------------------------------------------------------------------
__global__ __launch_bounds__(256) void gemm_att(
    const float* __restrict__ x,
    const unsigned short* __restrict__ Wt_hi,
    const unsigned short* __restrict__ Wt_lo,
    const float* __restrict__ att_s, const float* __restrict__ att_d,
    __hip_bfloat16* __restrict__ h, float* __restrict__ a_src_arr,
    float* __restrict__ a_dst_arr, int N,
    const int* __restrict__ dstA, int* __restrict__ cnt,
    int* __restrict__ rank, int E)
{
    int t      = threadIdx.x;
    int gtid   = blockIdx.x * blockDim.x + t;
    int stride = gridDim.x * blockDim.x;

    int i0 = gtid, i1 = gtid + stride, i2 = gtid + 2 * stride,
        i3 = gtid + 3 * stride;
    int r0 = 0, r1 = 0, r2 = 0, r3 = 0;
    bool early = ((t >> 6) & 1) == 0;   // waves 0,2 early; 1,3 late

    if (early) {
        if (i0 < E) r0 = atomicAdd(&cnt[dstA[i0]], 1);
        if (i1 < E) r1 = atomicAdd(&cnt[dstA[i1]], 1);
        if (i2 < E) r2 = atomicAdd(&cnt[dstA[i2]], 1);
        if (i3 < E) r3 = atomicAdd(&cnt[dstA[i3]], 1);
    }
    // generality tail (never taken at N=100K/E=1.6M): store immediately
    for (int i = gtid + 4 * stride; i < E; i += stride)
        rank[i] = atomicAdd(&cnt[dstA[i]], 1);

    // ---- GEMM ----
    int gw  = gtid >> 6;     // global wave id
    int l   = t & 63;
    int lm  = l & 15;        // x-row within rowtile / W-col within coltile
    int grp = l >> 4;        // k-subchunk 8*grp..8*grp+7 ; D cols grp*4+j
    int row0 = gw * 16;

    int srow = row0 + lm; if (srow >= N) srow = N - 1;
    const float* xq = x + (size_t)srow * K_IN + grp * 8;

    const unsigned short* wbh = Wt_hi + (size_t)lm * K_IN + grp * 8;
    const unsigned short* wbl = Wt_lo + (size_t)lm * K_IN + grp * 8;

    f32x4 acc[4];
#pragma unroll
    for (int n = 0; n < 4; ++n) acc[n] = (f32x4){0.f, 0.f, 0.f, 0.f};

    float4 xa = *(const float4*)(xq);
    float4 xb = *(const float4*)(xq + 4);

    for (int kt = 0; kt < K_IN / 32; ++kt) {
        float4 xa2, xb2;
        if (kt < K_IN / 32 - 1) {   // prefetch next k-chunk
            xa2 = *(const float4*)(xq + (kt + 1) * 32);
            xb2 = *(const float4*)(xq + (kt + 1) * 32 + 4);
        }
        // convert 8 f32 -> hi/lo bf16x8 (Markidis split, ~f32 accuracy)
        short sh[8], sl[8];
        const float* fa = (const float*)&xa;
        const float* fb = (const float*)&xb;
#pragma unroll
        for (int i = 0; i < 4; ++i) {
            float v0 = fa[i], v1 = fb[i];
            unsigned short h0 = bf16_rne(v0), h1 = bf16_rne(v1);
            sh[i] = (short)h0; sh[i + 4] = (short)h1;
            sl[i]     = (short)bf16_rne(v0 - __uint_as_float((unsigned)h0 << 16));
            sl[i + 4] = (short)bf16_rne(v1 - __uint_as_float((unsigned)h1 << 16));
        }
        bf16x8 xh = *(bf16x8*)&sh[0];
        bf16x8 xl = *(bf16x8*)&sl[0];

        int ko = kt * 32;
#pragma unroll
        for (int n = 0; n < 4; ++n) {
            bf16x8 wh = *(const bf16x8*)(wbh + (size_t)n * 16 * K_IN + ko);
            bf16x8 wl = *(const bf16x8*)(wbl + (size_t)n * 16 * K_IN + ko);
            acc[n] = __builtin_amdgcn_mfma_f32_16x16x32_bf16(wh, xh, acc[n], 0, 0, 0);
            acc[n] = __builtin_amdgcn_mfma_f32_16x16x32_bf16(wl, xh, acc[n], 0, 0, 0);
            acc[n] = __builtin_amdgcn_mfma_f32_16x16x32_bf16(wh, xl, acc[n], 0, 0, 0);
        }
        xa = xa2; xb = xb2;
    }

    // ---- epilogue: scores + bf16 h store ----
    int row = row0 + lm;
    float ps = 0.f, pd = 0.f;
#pragma unroll
    for (int n = 0; n < 4; ++n) {
        float4 as4 = *(const float4*)(att_s + n * 16 + grp * 4);
        float4 ad4 = *(const float4*)(att_d + n * 16 + grp * 4);
        f32x4 a = acc[n];
        ps += a.x * as4.x + a.y * as4.y + a.z * as4.z + a.w * as4.w;
        pd += a.x * ad4.x + a.y * ad4.y + a.z * ad4.z + a.w * ad4.w;
    }
    ps += __shfl_xor(ps, 16, 64); ps += __shfl_xor(ps, 32, 64);
    pd += __shfl_xor(pd, 16, 64); pd += __shfl_xor(pd, 32, 64);
    if (row < N) {
        if (grp == 0) { a_src_arr[row] = ps; a_dst_arr[row] = pd; }
#pragma unroll
        for (int n = 0; n < 4; ++n) {
            f32x4 a = acc[n];
            __hip_bfloat16 b0 = __float2bfloat16(a.x);
            __hip_bfloat16 b1 = __float2bfloat16(a.y);
            __hip_bfloat16 b2 = __float2bfloat16(a.z);
            __hip_bfloat16 b3 = __float2bfloat16(a.w);
            unsigned long long pk =
                (unsigned long long)*(unsigned short*)&b0 |
                ((unsigned long long)*(unsigned short*)&b1 << 16) |
                ((unsigned long long)*(unsigned short*)&b2 << 32) |
                ((unsigned long long)*(unsigned short*)&b3 << 48);
            *(unsigned long long*)(h + (size_t)row * C_OUT + n * 16 + grp * 4) = pk;
        }
    }

    // ---- late waves: issue atomics now (overlapped by early waves' GEMM
    // was already consumed; these drain under other blocks' tails) ----
    if (!early) {
        if (i0 < E) r0 = atomicAdd(&cnt[dstA[i0]], 1);
        if (i1 < E) r1 = atomicAdd(&cnt[dstA[i1]], 1);
        if (i2 < E) r2 = atomicAdd(&cnt[dstA[i2]], 1);
        if (i3 < E) r3 = atomicAdd(&cnt[dstA[i3]], 1);
    }

    // ---- store captured ranks ----
    if (i0 < E) rank[i0] = r0;
    if (i1 < E) rank[i1] = r1;
    if (i2 < E) rank[i2] = r2;
    if (i3 < E) rank[i3] = r3;
}

// ---------------------------------------------------------------------------
// Scan over counts (self loops folded into gat_pull, no +1).
// ---------------------------------------------------------------------------
__global__ __launch_bounds__(256) void scan_p1(
    const int* __restrict__ cnt, int* __restrict__ partials, int n)
{
    int b = blockIdx.x, t = threadIdx.x;
    int base = b * 1024;
    int s = 0;
#pragma unroll
    for (int j = 0; j < 4; ++j) {
        int i = base + t * 4 + j;
        if (i < n) s += cnt[i];
    }
    for (int d = 1; d < 64; d <<= 1) s += __shfl_xor(s, d, 64);
    __shared__ int wsum[4];
    int lane = t & 63, wid = t >> 6;
    if (lane == 0) wsum[wid] = s;
    __syncthreads();
    if (t == 0) partials[b] = wsum[0] + wsum[1] + wsum[2] + wsum[3];
}

__global__ __launch_bounds__(256) void scan_p2(int* partials, int nb)
{
    __shared__ int buf[256];
    int t = threadIdx.x;
    int v = (t < nb) ? partials[t] : 0;
    buf[t] = v;
    __syncthreads();
    for (int d = 1; d < 256; d <<= 1) {
        int w = (t >= d) ? buf[t - d] : 0;
        __syncthreads();
        buf[t] += w;
        __syncthreads();
    }
    if (t < nb) partials[t] = buf[t] - v;  // exclusive
}

__global__ __launch_bounds__(256) void scan_p3(
    const int* __restrict__ cnt, const int* __restrict__ partials,
    int* __restrict__ offsets, int n)
{
    int b = blockIdx.x, t = threadIdx.x;
    int base = b * 1024;
    int v[4];
    int s = 0;
#pragma unroll
    for (int j = 0; j < 4; ++j) {
        int i = base + t * 4 + j;
        v[j] = (i < n) ? cnt[i] : 0;
        s += v[j];
    }
    int lane = t & 63, wid = t >> 6;
    int incl = s;
    for (int d = 1; d < 64; d <<= 1) {
        int w = __shfl_up(incl, d, 64);
        if (lane >= d) incl += w;
    }
    __shared__ int wsum[4];
    __shared__ int wbase[4];
    if (lane == 63) wsum[wid] = incl;
    __syncthreads();
    if (t == 0) {
        int r = 0;
        for (int i = 0; i < 4; ++i) { wbase[i] = r; r += wsum[i]; }
    }
    __syncthreads();
    int run = partials[b] + wbase[wid] + (incl - s);
#pragma unroll
    for (int j = 0; j < 4; ++j) {
        int i = base + t * 4 + j;
        if (i < n) {
            offsets[i] = run;
            run += v[j];
            if (i == n - 1) offsets[n] = run;
        }
    }
}

// ---------------------------------------------------------------------------
// scatter_edges, ATOMIC-FREE: pos = offs[d] + rank[i] (rank captured from
// the histogram's returning atomic in gemm_att). r6 verified: removing the
// cursor atomics cut downstream time ~24us.
// ---------------------------------------------------------------------------
__global__ __launch_bounds__(256) void scatter_edges(
    const int* __restrict__ srcA, const int* __restrict__ dstA,
    const int* __restrict__ offsets, const int* __restrict__ rank,
    const float* __restrict__ a_src, const float* __restrict__ a_dst,
    unsigned long long* __restrict__ csr, int E)
{
    int i = blockIdx.x * blockDim.x + threadIdx.x;
    if (i >= E) return;
    int s = srcA[i], d = dstA[i];
    float e = a_src[s] + a_dst[d];
    e = fmaxf(e, NEG_SLOPE * e);
    float w = __expf(e);
    int pos = offsets[d] + rank[i];
    unsigned long long packed =
        (unsigned long long)(unsigned)s |
        ((unsigned long long)__float_as_uint(w) << 32);
    __builtin_nontemporal_store(packed, &csr[pos]);
}

// ---------------------------------------------------------------------------
// Kernel C: QUARTER-WAVE per node — 16 lanes/node, lane covers 4 bf16 cols
// (one 8B load per edge). Self-loop term computed analytically.
// ---------------------------------------------------------------------------
__global__ __launch_bounds__(256) void gat_pull(
    const int* __restrict__ offsets, const int2* __restrict__ csr,
    const unsigned short* __restrict__ h, const float* __restrict__ a_src,
    const float* __restrict__ a_dst, const float* __restrict__ bias,
    float* __restrict__ out, int N)
{
    int gw   = (blockIdx.x * blockDim.x + threadIdx.x) >> 6;  // wave id
    int lane = threadIdx.x & 63;
    int grp  = lane >> 4;        // 0..3 : node within wave
    int gl   = lane & 15;        // lane within group; cols 4*gl..4*gl+3
    int node = gw * 4 + grp;
    bool valid = node < N;
    int nv = valid ? node : 0;

    int beg = offsets[nv];
    int n   = valid ? (offsets[nv + 1] - beg) : 0;   // may be 0
    const int2* ce = csr + (n ? beg : 0);

    // self-loop term (always present in reference softmax)
    float asv = a_src[nv], adv = a_dst[nv];
    float es = asv + adv; es = fmaxf(es, NEG_SLOPE * es);
    float ws = __expf(es);
    unsigned long long hu = *(const unsigned long long*)
        (h + (size_t)nv * C_OUT + 4 * gl);
    unsigned hl = (unsigned)hu, hh = (unsigned)(hu >> 32);
    float acc0 = ws * __uint_as_float(hl << 16);
    float acc1 = ws * __uint_as_float(hl & 0xffff0000u);
    float acc2 = ws * __uint_as_float(hh << 16);
    float acc3 = ws * __uint_as_float(hh & 0xffff0000u);
    float den = ws;

    // 2-deep pipelined edge loop
    int2 c0 = ce[0];
    int2 c1 = ce[(n > 1) ? 1 : 0];
    unsigned long long u0 = *(const unsigned long long*)
        (h + (size_t)c0.x * C_OUT + 4 * gl);
    unsigned long long u1 = *(const unsigned long long*)
        (h + (size_t)c1.x * C_OUT + 4 * gl);

    for (int p = 0; p < n; p += 2) {
        int2 m0 = ce[(p + 2 < n) ? p + 2 : 0];
        int2 m1 = ce[(p + 3 < n) ? p + 3 : 0];
        unsigned long long v0 = *(const unsigned long long*)
            (h + (size_t)m0.x * C_OUT + 4 * gl);
        unsigned long long v1 = *(const unsigned long long*)
            (h + (size_t)m1.x * C_OUT + 4 * gl);

        float w0 = __int_as_float(c0.y);
        float w1 = (p + 1 < n) ? __int_as_float(c1.y) : 0.f;
        unsigned l0 = (unsigned)u0, h0 = (unsigned)(u0 >> 32);
        unsigned l1 = (unsigned)u1, h1 = (unsigned)(u1 >> 32);
        den  += w0 + w1;
        acc0 += w0 * __uint_as_float(l0 << 16)
              + w1 * __uint_as_float(l1 << 16);
        acc1 += w0 * __uint_as_float(l0 & 0xffff0000u)
              + w1 * __uint_as_float(l1 & 0xffff0000u);
        acc2 += w0 * __uint_as_float(h0 << 16)
              + w1 * __uint_as_float(h1 << 16);
        acc3 += w0 * __uint_as_float(h0 & 0xffff0000u)
              + w1 * __uint_as_float(h1 & 0xffff0000u);

        c0 = m0; c1 = m1; u0 = v0; u1 = v1;
    }

    float4 bl = *(const float4*)(bias + 4 * gl);
    float rd = 1.f / den;
    float o0 = acc0 * rd + bl.x;
    float o1 = acc1 * rd + bl.y;
    float o2 = acc2 * rd + bl.z;
    float o3 = acc3 * rd + bl.w;

    // L2 norm within the 16-lane group (xor d=1..8 stays in-group)
    float sq = o0 * o0 + o1 * o1 + o2 * o2 + o3 * o3;
#pragma unroll
    for (int d = 1; d < 16; d <<= 1) sq += __shfl_xor(sq, d, 64);
    float rn = 1.f / fmaxf(sqrtf(sq), EPS_NRM);

    if (valid)
        *(float4*)(out + (size_t)node * C_OUT + 4 * gl) =
            make_float4(o0 * rn, o1 * rn, o2 * rn, o3 * rn);
}

// ---------------------------------------------------------------------------
extern "C" void kernel_launch(void* const* d_in, const int* in_sizes, int n_in,
                              void* d_out, int out_size, void* d_ws, size_t ws_size,
                              hipStream_t stream)
{
    const float* x     = (const float*)d_in[0];
    const int*   ei    = (const int*)d_in[1];   // [2][E], row0=src, row1=dst
    const float* W     = (const float*)d_in[2];
    const float* att_s = (const float*)d_in[3];
    const float* att_d = (const float*)d_in[4];
    const float* bias  = (const float*)d_in[5];
    float*       out   = (float*)d_out;

    const int OUT = in_sizes[3];          // 64
    const int IN  = in_sizes[2] / OUT;    // 256
    const int N   = in_sizes[0] / IN;     // 100000
    const int E   = in_sizes[1] / 2;      // 1600000

    // workspace carve-out (256B aligned) — ~34 MB total
    char* w = (char*)d_ws;
    auto alloc = [&](size_t bytes) -> void* {
        void* p = (void*)w;
        w += (bytes + 255) & ~(size_t)255;
        return p;
    };
    __hip_bfloat16* h = (__hip_bfloat16*)alloc((size_t)N * C_OUT * 2);
    float* a_src  = (float*)alloc((size_t)N * 4);
    float* a_dst  = (float*)alloc((size_t)N * 4);
    int*   cnt    = (int*)alloc((size_t)N * 4);
    int*   offs   = (int*)alloc((size_t)(N + 1) * 4);
    int*   parts  = (int*)alloc(1024 * 4);
    unsigned short* Wt_hi = (unsigned short*)alloc((size_t)K_IN * C_OUT * 2);
    unsigned short* Wt_lo = (unsigned short*)alloc((size_t)K_IN * C_OUT * 2);
    int*   rank   = (int*)alloc((size_t)E * 4);
    unsigned long long* csr = (unsigned long long*)alloc((size_t)E * 8);

    hipMemsetAsync(cnt, 0, (size_t)N * 4, stream);

    wsplit<<<(K_IN * C_OUT + 255) / 256, 256, 0, stream>>>(W, Wt_hi, Wt_lo);

    // 16 rows per wave, 4 waves per block -> 64 rows/block
    gemm_att<<<(N + 63) / 64, 256, 0, stream>>>(
        x, Wt_hi, Wt_lo, att_s, att_d, h, a_src, a_dst, N, ei + E, cnt,
        rank, E);

    int NB = (N + 1023) / 1024;
    scan_p1<<<NB, 256, 0, stream>>>(cnt, parts, N);
    scan_p2<<<1, 256, 0, stream>>>(parts, NB);
    scan_p3<<<NB, 256, 0, stream>>>(cnt, parts, offs, N);

    scatter_edges<<<(E + 255) / 256, 256, 0, stream>>>(
        ei, ei + E, offs, rank, a_src, a_dst, csr, E);

    // quarter-wave: 16 nodes per 256-thread block
    gat_pull<<<(N + 15) / 16, 256, 0, stream>>>(offs, (const int2*)csr,
        (const unsigned short*)h, a_src, a_dst, bias, out, N);
}